// Round 4
// baseline (158.889 us; speedup 1.0000x reference)
//
#include <hip/hip_runtime.h>
#include <cstdint>
#include <cstddef>

#define BATCH 64
#define NIN   1024
#define CIN   256
#define NC    32
#define NJC   16     // j-blocks per batch (64 j each)
#define JCH   64
#define T_EPS 1e-7f
#define CT_S  72     // cT row stride in u16 (144 B)

typedef __attribute__((ext_vector_type(8))) short short8;   // 8 bf16 = 4 VGPR
typedef __attribute__((ext_vector_type(4))) float floatx4;  // MFMA 16x16 acc

__device__ __forceinline__ unsigned short bf16rne(float f) {
  unsigned int u = __float_as_uint(f);
  u += 0x7FFFu + ((u >> 16) & 1u);
  return (unsigned short)(u >> 16);
}
__device__ __forceinline__ float bf2f(unsigned short h) {
  return __uint_as_float(((unsigned int)h) << 16);
}
// swizzled u16 index into the 64x256 LDS x-tile (16B chunks XOR-permuted per j)
__device__ __forceinline__ int xsw(int j, int c) {
  return j * 256 + ((((c >> 3) ^ (j & 7) ^ ((j >> 3) & 7)) << 3) | (c & 7));
}

union USH {
  unsigned short cT[NC * CT_S]; // 4.5 KB (fused softmax coeffs)
};

// ---- K1: colsum partials + Wi/WiT build (b==0) ----------------------------
// grid (jc=16, b=64). x read warms L3 for the two k_fusedf passes.
// Wi[i][c][k] (for wt-gen b128 reads) ; WiT[i][k][c] (for s-dot b128 reads).
__global__ __launch_bounds__(256) void k_colsum(const float* __restrict__ x,
                                                const float* __restrict__ W,
                                                unsigned short* __restrict__ Wi,
                                                unsigned short* __restrict__ WiT,
                                                float* __restrict__ y0p) {
  const int jc = blockIdx.x, b = blockIdx.y, t = threadIdx.x;
  const int jj = t >> 6, c4 = t & 63;
  __shared__ float4 red[4][64];
  const float4* xg = (const float4*)(x + ((size_t)(b * NIN + jc * JCH)) * CIN);
  float4 acc = make_float4(0.f, 0.f, 0.f, 0.f);
  #pragma unroll
  for (int jr = 0; jr < 16; ++jr) {
    int j = jr * 4 + jj;
    float4 v = xg[j * 64 + c4];
    acc.x += v.x; acc.y += v.y; acc.z += v.z; acc.w += v.w;
  }
  red[jj][c4] = acc;
  if (b == 0) {
    // build Wi/WiT rows for i = jc*2, jc*2+1 ; thread t <-> c
    #pragma unroll
    for (int i2 = 0; i2 < 2; ++i2) {
      int i = jc * 2 + i2;
      const float4* wsrc = (const float4*)(W + (size_t)t * 1024 + i * 32);
      unsigned short* wdst = Wi + ((size_t)i * CIN + t) * NC;
      unsigned short* wtd  = WiT + (size_t)i * 32 * CIN + t;
      #pragma unroll
      for (int k4 = 0; k4 < 8; ++k4) {
        float4 v = wsrc[k4];
        ushort4 h;
        h.x = bf16rne(v.x); h.y = bf16rne(v.y);
        h.z = bf16rne(v.z); h.w = bf16rne(v.w);
        *(ushort4*)&wdst[k4 * 4] = h;
        // transposed copy: WiT[(i*32+k)*256 + c], coalesced across t per k
        wtd[(size_t)(k4 * 4 + 0) * CIN] = h.x;
        wtd[(size_t)(k4 * 4 + 1) * CIN] = h.y;
        wtd[(size_t)(k4 * 4 + 2) * CIN] = h.z;
        wtd[(size_t)(k4 * 4 + 3) * CIN] = h.w;
      }
    }
  }
  __syncthreads();
  if (t < 64) {
    float4 s = red[0][t];
    #pragma unroll
    for (int p = 1; p < 4; ++p) {
      s.x += red[p][t].x; s.y += red[p][t].y;
      s.z += red[p][t].z; s.w += red[p][t].w;
    }
    *(float4*)&y0p[(b * NJC + jc) * CIN + t * 4] = s;
  }
}

// ---- K2: y-reduce -> s = y@W_i -> squash -> wt(bf16) or out ---------------
// grid (i=NC, b=BATCH). MODE 0: yin=y0p fp32 (scale 1/32). MODE 1: yin=ypart
// bf16 [b][jc][i][c], write wt. MODE 2: write out.
// Weight fragments prefetched at top (b128) so L2 latency hides under the
// y-reduction; s-dot uses WiT (vector loads) instead of 32 scalar u16.
template <int MODE>
__global__ __launch_bounds__(256) void k_post(const void* __restrict__ yin,
                                              const unsigned short* __restrict__ Wi,
                                              const unsigned short* __restrict__ WiT,
                                              unsigned short* __restrict__ wtout,
                                              float* __restrict__ outg) {
  const int i = blockIdx.x, b = blockIdx.y, t = threadIdx.x;
  const int k = t & 31, g = t >> 5;
  __shared__ float ys[CIN];
  __shared__ float sred[8][32];
  __shared__ float os[NC];
  // early-issue: WiT chunk for s-dot (this thread's (k, c-quarter))
  short8 wv[4];
  {
    const short8* wtrow = (const short8*)(WiT + ((size_t)i * 32 + k) * CIN + g * 32);
    #pragma unroll
    for (int m = 0; m < 4; ++m) wv[m] = wtrow[m];
  }
  // early-issue: Wi row for wt-gen (only needed when producing wt)
  short8 wr[4];
  if constexpr (MODE != 2) {
    const short8* wrow = (const short8*)(Wi + ((size_t)i * CIN + t) * NC);
    #pragma unroll
    for (int m = 0; m < 4; ++m) wr[m] = wrow[m];
  }
  // step 1: reduce partial y for (b,i); lane t <-> c
  float a = 0.f;
  if (MODE == 0) {
    const float* y0p = (const float*)yin;
    #pragma unroll
    for (int p = 0; p < NJC; ++p) a += y0p[(b * NJC + p) * CIN + t];
    a *= (1.f / 32.f);
  } else {
    const unsigned short* yp = (const unsigned short*)yin;
    #pragma unroll
    for (int p = 0; p < NJC; ++p)
      a += bf2f(yp[(((size_t)(b * NJC + p)) * NC + i) * CIN + t]);
  }
  ys[t] = a;
  __syncthreads();
  // step 2: s[k] partials over this thread's c-quarter (broadcast ys reads)
  {
    float ps = 0.f;
    #pragma unroll
    for (int m = 0; m < 4; ++m)
      #pragma unroll
      for (int e = 0; e < 8; ++e)
        ps += ys[g * 32 + m * 8 + e] * bf2f((unsigned short)wv[m][e]);
    sred[g][k] = ps;
  }
  __syncthreads();
  float s = 0.f;
  #pragma unroll
  for (int g8 = 0; g8 < 8; ++g8) s += sred[g8][k];
  float s2 = s * s;
  #pragma unroll
  for (int m = 1; m < 32; m <<= 1) s2 += __shfl_xor(s2, m);
  float o = s * rsqrtf(s2 + T_EPS);
  if constexpr (MODE == 2) {
    if (t < 32) outg[((size_t)b * NC + i) * 32 + t] = o;
  } else {
    if (t < 32) os[t] = o;
    __syncthreads();
    // step 4: wt[b,i,c=t] = sum_k os[k] * Wi[i][t][k]  (prefetched b128)
    float acc = 0.f;
    #pragma unroll
    for (int k8 = 0; k8 < 4; ++k8) {
      #pragma unroll
      for (int e = 0; e < 8; ++e)
        acc += os[k8 * 8 + e] * bf2f((unsigned short)wr[k8][e]);
    }
    wtout[((size_t)b * NC + i) * CIN + t] = bf16rne(acc);
  }
}

// ---- fused routing iteration core (A-phase takes prefetched ks=0,1 frags) -
__device__ __forceinline__ void fused_iter(int b, int t,
                                           const unsigned short* xs, USH* u,
                                           const unsigned short* __restrict__ wt,
                                           short8 a0p0, short8 a1p0,
                                           short8 a0p1, short8 a1p1,
                                           unsigned short* __restrict__ yo) {
  const int w = t >> 6, l16 = t & 15, q = (t >> 4) & 3;
  const int jloc = w * 16 + l16;
  const unsigned short* wrow = wt + (size_t)b * NC * CIN;
  floatx4 accA0 = {0.f, 0.f, 0.f, 0.f}, accA1 = {0.f, 0.f, 0.f, 0.f};
  // ks = 0,1 from prefetch (issued before staging barrier)
  {
    short8 bx0 = *(const short8*)&xs[xsw(jloc, 0 * 32 + q * 8)];
    accA0 = __builtin_amdgcn_mfma_f32_16x16x32_bf16(a0p0, bx0, accA0, 0, 0, 0);
    accA1 = __builtin_amdgcn_mfma_f32_16x16x32_bf16(a1p0, bx0, accA1, 0, 0, 0);
    short8 bx1 = *(const short8*)&xs[xsw(jloc, 1 * 32 + q * 8)];
    accA0 = __builtin_amdgcn_mfma_f32_16x16x32_bf16(a0p1, bx1, accA0, 0, 0, 0);
    accA1 = __builtin_amdgcn_mfma_f32_16x16x32_bf16(a1p1, bx1, accA1, 0, 0, 0);
  }
  #pragma unroll
  for (int ks = 2; ks < 8; ++ks) {
    short8 bx = *(const short8*)&xs[xsw(jloc, ks * 32 + q * 8)];
    short8 a0 = *(const short8*)(wrow + (size_t)l16 * CIN + ks * 32 + q * 8);
    short8 a1 = *(const short8*)(wrow + (size_t)(16 + l16) * CIN + ks * 32 + q * 8);
    accA0 = __builtin_amdgcn_mfma_f32_16x16x32_bf16(a0, bx, accA0, 0, 0, 0);
    accA1 = __builtin_amdgcn_mfma_f32_16x16x32_bf16(a1, bx, accA1, 0, 0, 0);
  }
  {
    float m = accA0[0];
    #pragma unroll
    for (int r = 1; r < 4; ++r) m = fmaxf(m, accA0[r]);
    #pragma unroll
    for (int r = 0; r < 4; ++r) m = fmaxf(m, accA1[r]);
    m = fmaxf(m, __shfl_xor(m, 16));
    m = fmaxf(m, __shfl_xor(m, 32));
    float e0[4], e1[4], s = 0.f;
    #pragma unroll
    for (int r = 0; r < 4; ++r) {
      e0[r] = __expf(accA0[r] - m);
      e1[r] = __expf(accA1[r] - m);
      s += e0[r] + e1[r];
    }
    s += __shfl_xor(s, 16);
    s += __shfl_xor(s, 32);
    float rs = 1.f / s;
    #pragma unroll
    for (int r = 0; r < 4; ++r) {
      u->cT[(q * 4 + r) * CT_S + jloc]      = bf16rne(e0[r] * rs);
      u->cT[(16 + q * 4 + r) * CT_S + jloc] = bf16rne(e1[r] * rs);
    }
  }
  __syncthreads();
  const int cw = w * 64;
  floatx4 accB[2][4];
  #pragma unroll
  for (int h = 0; h < 2; ++h)
    #pragma unroll
    for (int ct = 0; ct < 4; ++ct) accB[h][ct] = (floatx4){0.f, 0.f, 0.f, 0.f};
  #pragma unroll
  for (int ks = 0; ks < 2; ++ks) {
    short8 ca0 = *(const short8*)&u->cT[l16 * CT_S + ks * 32 + q * 8];
    short8 ca1 = *(const short8*)&u->cT[(16 + l16) * CT_S + ks * 32 + q * 8];
    #pragma unroll
    for (int ct = 0; ct < 4; ++ct) {
      const int c = cw + ct * 16 + l16;
      short8 xf;
      #pragma unroll
      for (int e = 0; e < 8; ++e)
        xf[e] = (short)xs[xsw(ks * 32 + q * 8 + e, c)];
      accB[0][ct] = __builtin_amdgcn_mfma_f32_16x16x32_bf16(ca0, xf, accB[0][ct], 0, 0, 0);
      accB[1][ct] = __builtin_amdgcn_mfma_f32_16x16x32_bf16(ca1, xf, accB[1][ct], 0, 0, 0);
    }
  }
  #pragma unroll
  for (int h = 0; h < 2; ++h)
    #pragma unroll
    for (int ct = 0; ct < 4; ++ct)
      #pragma unroll
      for (int r = 0; r < 4; ++r) {
        int i = h * 16 + q * 4 + r;
        int c = cw + ct * 16 + l16;
        yo[i * CIN + c] = bf16rne(accB[h][ct][r]);
      }
}

// ---- K3/K5: fused iteration reading x fp32 (L3-hot), convert in staging ---
__global__ __launch_bounds__(256, 4) void k_fusedf(const float* __restrict__ x,
                                                   const unsigned short* __restrict__ wt,
                                                   unsigned short* __restrict__ ypart) {
  const int jc = blockIdx.x, b = blockIdx.y, t = threadIdx.x;
  const int l16 = t & 15, q = (t >> 4) & 3;
  __shared__ unsigned short xs[64 * 256];    // 32 KB, swizzled
  __shared__ USH u;
  // prefetch wt a-fragments for ks=0,1 — independent of LDS, loads stay in
  // flight across the staging loop + barrier
  const unsigned short* wrow = wt + (size_t)b * NC * CIN;
  short8 a0p0 = *(const short8*)(wrow + (size_t)l16 * CIN + 0 * 32 + q * 8);
  short8 a1p0 = *(const short8*)(wrow + (size_t)(16 + l16) * CIN + 0 * 32 + q * 8);
  short8 a0p1 = *(const short8*)(wrow + (size_t)l16 * CIN + 1 * 32 + q * 8);
  short8 a1p1 = *(const short8*)(wrow + (size_t)(16 + l16) * CIN + 1 * 32 + q * 8);
  {
    const int jj = t >> 6, c4 = t & 63;
    const float4* xg = (const float4*)(x + ((size_t)(b * NIN + jc * JCH)) * CIN);
    #pragma unroll
    for (int jr = 0; jr < 16; ++jr) {
      int j = jr * 4 + jj;
      float4 v = xg[j * 64 + c4];
      ushort4 h;
      h.x = bf16rne(v.x); h.y = bf16rne(v.y);
      h.z = bf16rne(v.z); h.w = bf16rne(v.w);
      // c = c4*4: low 3 bits 0 or 4 -> stays inside one 8-elem chunk, xsw-safe
      *(ushort4*)&xs[xsw(j, c4 * 4)] = h;
    }
  }
  __syncthreads();
  fused_iter(b, t, xs, &u, wt, a0p0, a1p0, a0p1, a1p1,
             ypart + ((size_t)(b * NJC + jc)) * NC * CIN);
}

// ===========================================================================

extern "C" void kernel_launch(void* const* d_in, const int* in_sizes, int n_in,
                              void* d_out, int out_size, void* d_ws, size_t ws_size,
                              hipStream_t stream) {
  (void)in_sizes; (void)n_in; (void)out_size; (void)ws_size;
  const float* x = (const float*)d_in[0];
  const float* W = (const float*)d_in[1];
  float* out = (float*)d_out;
  char* ws = (char*)d_ws;
  // ws: wt 1MiB @0 | ypart 16MiB @1M | y0p 1MiB @17M | Wi 512K @18M | WiT 512K @18.5M
  unsigned short* wtb   = (unsigned short*)ws;
  unsigned short* ypart = (unsigned short*)(ws + (1ull << 20));
  float*          y0p   = (float*)(ws + (17ull << 20));
  unsigned short* Wi    = (unsigned short*)(ws + (18ull << 20));
  unsigned short* WiT   = (unsigned short*)(ws + (18ull << 20) + (512ull << 10));

  dim3 gfuse(NJC, BATCH);     // (16, 64)
  dim3 gpost(NC, BATCH);      // (32, 64)
  k_colsum<<<gfuse, 256, 0, stream>>>(x, W, Wi, WiT, y0p);
  k_post<0><<<gpost, 256, 0, stream>>>(y0p, Wi, WiT, wtb, nullptr);    // iter 0
  k_fusedf<<<gfuse, 256, 0, stream>>>(x, wtb, ypart);                  // iter 1
  k_post<1><<<gpost, 256, 0, stream>>>(ypart, Wi, WiT, wtb, nullptr);
  k_fusedf<<<gfuse, 256, 0, stream>>>(x, wtb, ypart);                  // iter 2
  k_post<2><<<gpost, 256, 0, stream>>>(ypart, Wi, WiT, nullptr, out);
}